// Round 1
// baseline (288.802 us; speedup 1.0000x reference)
//
#include <hip/hip_runtime.h>

typedef _Float16 f16x8 __attribute__((ext_vector_type(8)));
typedef float f32x4 __attribute__((ext_vector_type(4)));

#define L_SZ 4096

__device__ __forceinline__ unsigned short f2h(float f) {
    _Float16 h = (_Float16)f;
    return __builtin_bit_cast(unsigned short, h);
}

// ---------------- K0: convert weights fp32 -> fp16 ----------------
__global__ __launch_bounds__(256) void cvt_kernel(
    const float* __restrict__ wq, const float* __restrict__ wk,
    const float* __restrict__ wv, const float* __restrict__ fcw_f,
    unsigned short* __restrict__ Wc, unsigned short* __restrict__ fcw)
{
    int t = blockIdx.x * 256 + threadIdx.x;   // 65536 threads
    if (t < 16384)       Wc[t]           = f2h(wq[t]);
    else if (t < 32768)  Wc[t]           = f2h(wk[t - 16384]);
    else if (t < 49152)  Wc[t]           = f2h(wv[t - 32768]);
    else                 fcw[t - 49152]  = f2h(fcw_f[t - 49152]);
}

// ---------------- K1: QKV projection ----------------
// x:(b,128,L) fp32.  Out: Qp,Kp:(bh, l, 64) f16 token-major (Q scaled by log2e/8),
// Vp:(b, c, L) f16 d-major.
__global__ __launch_bounds__(256) void qkv_kernel(
    const float* __restrict__ x, const unsigned short* __restrict__ Wc,
    const float* __restrict__ bq, const float* __restrict__ bk, const float* __restrict__ bv,
    unsigned short* __restrict__ Qp, unsigned short* __restrict__ Kp, unsigned short* __restrict__ Vp)
{
    int blk = blockIdx.x;
    int b = blk >> 6;
    int l0 = (blk & 63) * 64;
    int tid = threadIdx.x;
    int wave = tid >> 6, lane = tid & 63;
    int c = lane & 15, qd = lane >> 4;

    __shared__ __align__(16) unsigned short Xs[64 * 128]; // [l][i], 16B chunk ci stored at ci^(l&15)

    #pragma unroll
    for (int it = 0; it < 8; ++it) {
        int i  = (tid >> 4) + 16 * it;
        int l4 = (tid & 15) * 4;
        const float4 v = *(const float4*)&x[(b * 128 + i) * L_SZ + l0 + l4];
        float vv[4] = {v.x, v.y, v.z, v.w};
        int ci = i >> 3;
        #pragma unroll
        for (int u = 0; u < 4; ++u) {
            int l = l4 + u;
            Xs[l * 128 + ((ci ^ (l & 15)) * 8) + (i & 7)] = f2h(vv[u]);
        }
    }
    __syncthreads();

    f16x8 afrag[4];
    #pragma unroll
    for (int kc = 0; kc < 4; ++kc) {
        int l = wave * 16 + c;
        int ci = kc * 4 + qd;
        afrag[kc] = *(const f16x8*)&Xs[l * 128 + ((ci ^ (l & 15)) * 8)];
    }

    f32x4 acc[24];
    #pragma unroll
    for (int nt = 0; nt < 24; ++nt) acc[nt] = (f32x4){0.f, 0.f, 0.f, 0.f};

    #pragma unroll
    for (int kc = 0; kc < 4; ++kc) {
        #pragma unroll
        for (int nt = 0; nt < 24; ++nt) {
            int o = nt * 16 + c;  // 0..383 row of Wc
            f16x8 bfrag = *(const f16x8*)&Wc[o * 128 + kc * 32 + qd * 8];
            acc[nt] = __builtin_amdgcn_mfma_f32_16x16x32_f16(afrag[kc], bfrag, acc[nt], 0, 0, 0);
        }
    }

    const float s_q = 0.18033688011f;  // log2(e)/8
    #pragma unroll
    for (int nt = 0; nt < 24; ++nt) {
        int p = nt >> 3;
        int o = (nt & 7) * 16 + c;     // 0..127
        int h = o >> 6, d = o & 63;
        #pragma unroll
        for (int r = 0; r < 4; ++r) {
            int l = l0 + wave * 16 + qd * 4 + r;
            float val = acc[nt][r];
            if (p == 0) {
                val = (val + bq[o]) * s_q;
                Qp[((b * 2 + h) * L_SZ + l) * 64 + d] = f2h(val);
            } else if (p == 1) {
                val += bk[o];
                Kp[((b * 2 + h) * L_SZ + l) * 64 + d] = f2h(val);
            } else {
                val += bv[o];
                Vp[(size_t)(b * 128 + o) * L_SZ + l] = f2h(val);
            }
        }
    }
}

// ---------------- K2: flash attention ----------------
// Grid 512 = bh(8) x ltile(64).  4 waves x 16 rows.  Out Ob: (b, c, l) f16.
__global__ __launch_bounds__(256) void attn_kernel(
    const unsigned short* __restrict__ Qp, const unsigned short* __restrict__ Kp,
    const unsigned short* __restrict__ Vp, unsigned short* __restrict__ Ob)
{
    int blk = blockIdx.x;
    int bh = blk >> 6;
    int l0 = (blk & 63) * 64;
    int b = bh >> 1, h = bh & 1;
    int tid = threadIdx.x;
    int wave = tid >> 6, lane = tid & 63;
    int c = lane & 15, qd = lane >> 4;

    __shared__ __align__(16) unsigned short Ks[64 * 64];    // [m][d], chunk^ (m&7)
    __shared__ __align__(16) unsigned short Vs[64 * 64];    // [d][m], chunk^ (d&7)
    __shared__ __align__(16) unsigned short Ps[4 * 16 * 64];// per-wave [l][m], chunk^ (l&7)

    const unsigned short* Qb = Qp + (size_t)bh * L_SZ * 64;
    const unsigned short* Kb = Kp + (size_t)bh * L_SZ * 64;
    const unsigned short* Vb = Vp + ((size_t)b * 128 + h * 64) * L_SZ;

    f16x8 qfrag[2];
    #pragma unroll
    for (int kc = 0; kc < 2; ++kc)
        qfrag[kc] = *(const f16x8*)&Qb[(l0 + wave * 16 + c) * 64 + kc * 32 + qd * 8];

    float m_st[4], l_st[4];
    f32x4 acc_o[4];
    #pragma unroll
    for (int r = 0; r < 4; ++r) { m_st[r] = -1e30f; l_st[r] = 0.f; }
    #pragma unroll
    for (int dt = 0; dt < 4; ++dt) acc_o[dt] = (f32x4){0.f, 0.f, 0.f, 0.f};

    unsigned short* Pw = &Ps[wave * 16 * 64];

    for (int mt = 0; mt < 64; ++mt) {
        int m0 = mt * 64;
        // global -> regs (issued before the barrier to overlap latency)
        uint4 kreg[2], vreg[2];
        #pragma unroll
        for (int it = 0; it < 2; ++it) {
            int u = tid + it * 256;
            int row = u >> 3, ci = u & 7;
            kreg[it] = *(const uint4*)&Kb[(m0 + row) * 64 + ci * 8];
            vreg[it] = *(const uint4*)&Vb[(size_t)row * L_SZ + m0 + ci * 8];
        }
        __syncthreads();   // prior iter's LDS reads complete
        #pragma unroll
        for (int it = 0; it < 2; ++it) {
            int u = tid + it * 256;
            int row = u >> 3, ci = u & 7;
            *(uint4*)&Ks[row * 64 + ((ci ^ (row & 7)) * 8)] = kreg[it];
            *(uint4*)&Vs[row * 64 + ((ci ^ (row & 7)) * 8)] = vreg[it];
        }
        __syncthreads();

        // S = (scaled Q) K^T : 4 n-tiles x 2 k-chunks
        f32x4 s[4];
        #pragma unroll
        for (int nt = 0; nt < 4; ++nt) {
            s[nt] = (f32x4){0.f, 0.f, 0.f, 0.f};
            #pragma unroll
            for (int kc = 0; kc < 2; ++kc) {
                int m = nt * 16 + c;
                int ci = kc * 4 + qd;
                f16x8 bf = *(const f16x8*)&Ks[m * 64 + ((ci ^ (m & 7)) * 8)];
                s[nt] = __builtin_amdgcn_mfma_f32_16x16x32_f16(qfrag[kc], bf, s[nt], 0, 0, 0);
            }
        }

        // online softmax (base-2 domain; log2e folded into Q)
        #pragma unroll
        for (int r = 0; r < 4; ++r) {
            float mx = fmaxf(fmaxf(s[0][r], s[1][r]), fmaxf(s[2][r], s[3][r]));
            mx = fmaxf(mx, __shfl_xor(mx, 1));
            mx = fmaxf(mx, __shfl_xor(mx, 2));
            mx = fmaxf(mx, __shfl_xor(mx, 4));
            mx = fmaxf(mx, __shfl_xor(mx, 8));
            float mnew = fmaxf(m_st[r], mx);
            float alpha = exp2f(m_st[r] - mnew);
            m_st[r] = mnew;
            l_st[r] *= alpha;
            #pragma unroll
            for (int dt = 0; dt < 4; ++dt) acc_o[dt][r] *= alpha;
            float rsum = 0.f;
            #pragma unroll
            for (int nt = 0; nt < 4; ++nt) {
                float p = exp2f(s[nt][r] - mnew);
                s[nt][r] = p;
                rsum += p;
            }
            rsum += __shfl_xor(rsum, 1);
            rsum += __shfl_xor(rsum, 2);
            rsum += __shfl_xor(rsum, 4);
            rsum += __shfl_xor(rsum, 8);
            l_st[r] += rsum;
        }

        // P (C-layout) -> LDS (A-layout source)
        #pragma unroll
        for (int nt = 0; nt < 4; ++nt) {
            #pragma unroll
            for (int r = 0; r < 4; ++r) {
                int l = qd * 4 + r, col = nt * 16 + c;
                int ci = col >> 3;
                Pw[l * 64 + ((ci ^ (l & 7)) * 8) + (col & 7)] = f2h(s[nt][r]);
            }
        }
        __syncthreads();

        // O += P V^T
        #pragma unroll
        for (int kc = 0; kc < 2; ++kc) {
            int ci = kc * 4 + qd;
            f16x8 pf = *(const f16x8*)&Pw[c * 64 + ((ci ^ (c & 7)) * 8)];
            #pragma unroll
            for (int dt = 0; dt < 4; ++dt) {
                int d = dt * 16 + c;
                f16x8 vf = *(const f16x8*)&Vs[d * 64 + ((ci ^ (d & 7)) * 8)];
                acc_o[dt] = __builtin_amdgcn_mfma_f32_16x16x32_f16(pf, vf, acc_o[dt], 0, 0, 0);
            }
        }
    }

    float inv_l[4];
    #pragma unroll
    for (int r = 0; r < 4; ++r) inv_l[r] = 1.0f / l_st[r];

    #pragma unroll
    for (int dt = 0; dt < 4; ++dt) {
        int d = dt * 16 + c;
        unsigned int p0 = (unsigned int)f2h(acc_o[dt][0] * inv_l[0]) |
                          ((unsigned int)f2h(acc_o[dt][1] * inv_l[1]) << 16);
        unsigned int p1 = (unsigned int)f2h(acc_o[dt][2] * inv_l[2]) |
                          ((unsigned int)f2h(acc_o[dt][3] * inv_l[3]) << 16);
        uint2 pk = make_uint2(p0, p1);
        *(uint2*)&Ob[(size_t)(b * 128 + h * 64 + d) * L_SZ + l0 + wave * 16 + qd * 4] = pk;
    }
}

// ---------------- K3: fc (over last dim) + BN + PReLU ----------------
// Ob rows r=(b*128+c)*32+hi, 128 wide. out fp32 same row layout.
__global__ __launch_bounds__(256) void fc_kernel(
    const unsigned short* __restrict__ Ob, const unsigned short* __restrict__ fcw,
    const float* __restrict__ fc_b, const float* __restrict__ bn_g,
    const float* __restrict__ bn_b, const float* __restrict__ bn_m,
    const float* __restrict__ bn_v, const float* __restrict__ prelu_a,
    float* __restrict__ out)
{
    int tid = threadIdx.x;
    int wave = tid >> 6, lane = tid & 63;
    int c = lane & 15, qd = lane >> 4;
    int r0 = blockIdx.x * 64 + wave * 16;

    f16x8 af[4];
    #pragma unroll
    for (int kc = 0; kc < 4; ++kc)
        af[kc] = *(const f16x8*)&Ob[(size_t)(r0 + c) * 128 + kc * 32 + qd * 8];

    f32x4 acc[8];
    #pragma unroll
    for (int nt = 0; nt < 8; ++nt) acc[nt] = (f32x4){0.f, 0.f, 0.f, 0.f};

    #pragma unroll
    for (int kc = 0; kc < 4; ++kc) {
        #pragma unroll
        for (int nt = 0; nt < 8; ++nt) {
            f16x8 bf = *(const f16x8*)&fcw[(nt * 16 + c) * 128 + kc * 32 + qd * 8];
            acc[nt] = __builtin_amdgcn_mfma_f32_16x16x32_f16(af[kc], bf, acc[nt], 0, 0, 0);
        }
    }

    float pa = prelu_a[0];
    #pragma unroll
    for (int r = 0; r < 4; ++r) {
        int row = r0 + qd * 4 + r;
        int ch = (row >> 5) & 127;
        float g  = bn_g[ch] * rsqrtf(bn_v[ch] + 1e-5f);
        float mn = bn_m[ch], bt = bn_b[ch];
        #pragma unroll
        for (int nt = 0; nt < 8; ++nt) {
            int o = nt * 16 + c;
            float y = (acc[nt][r] + fc_b[o] - mn) * g + bt;
            y = y > 0.f ? y : pa * y;
            out[(size_t)row * 128 + o] = y;
        }
    }
}

extern "C" void kernel_launch(void* const* d_in, const int* in_sizes, int n_in,
                              void* d_out, int out_size, void* d_ws, size_t ws_size,
                              hipStream_t stream) {
    const float* x     = (const float*)d_in[0];
    const float* wq    = (const float*)d_in[1];
    const float* bq    = (const float*)d_in[2];
    const float* wk    = (const float*)d_in[3];
    const float* bk    = (const float*)d_in[4];
    const float* wv    = (const float*)d_in[5];
    const float* bv    = (const float*)d_in[6];
    const float* fcw_f = (const float*)d_in[7];
    const float* fcb   = (const float*)d_in[8];
    const float* bn_g  = (const float*)d_in[9];
    const float* bn_b  = (const float*)d_in[10];
    const float* bn_m  = (const float*)d_in[11];
    const float* bn_v  = (const float*)d_in[12];
    const float* pa    = (const float*)d_in[13];
    float* out = (float*)d_out;

    unsigned short* Wc  = (unsigned short*)d_ws;   // 384*128
    unsigned short* fcw = Wc + 384 * 128;          // 128*128
    unsigned short* Qp  = fcw + 128 * 128;         // 8*4096*64 each below
    unsigned short* Kp  = Qp + 8 * L_SZ * 64;
    unsigned short* Vp  = Kp + 8 * L_SZ * 64;
    unsigned short* Obf = Vp + 8 * L_SZ * 64;

    hipLaunchKernelGGL(cvt_kernel,  dim3(256), dim3(256), 0, stream, wq, wk, wv, fcw_f, Wc, fcw);
    hipLaunchKernelGGL(qkv_kernel,  dim3(256), dim3(256), 0, stream, x, Wc, bq, bk, bv, Qp, Kp, Vp);
    hipLaunchKernelGGL(attn_kernel, dim3(512), dim3(256), 0, stream, Qp, Kp, Vp, Obf);
    hipLaunchKernelGGL(fc_kernel,   dim3(256), dim3(256), 0, stream, Obf, fcw, fcb, bn_g, bn_b, bn_m, bn_v, pa, out);
}

// Round 3
// 214.184 us; speedup vs baseline: 1.3484x; 1.3484x over previous
//
#include <hip/hip_runtime.h>

typedef _Float16 f16x8 __attribute__((ext_vector_type(8)));
typedef __fp16 h16x2 __attribute__((ext_vector_type(2)));
typedef float f32x4 __attribute__((ext_vector_type(4)));
typedef float f32x16 __attribute__((ext_vector_type(16)));

#define L_SZ 4096

__device__ __forceinline__ unsigned short f2h(float f) {
    _Float16 h = (_Float16)f;
    return __builtin_bit_cast(unsigned short, h);
}

__device__ __forceinline__ unsigned int pk2(float a, float b) {
    h16x2 p = __builtin_amdgcn_cvt_pkrtz(a, b);
    return __builtin_bit_cast(unsigned int, p);
}

// ---------------- K0: convert weights fp32 -> fp16 ----------------
__global__ __launch_bounds__(256) void cvt_kernel(
    const float* __restrict__ wq, const float* __restrict__ wk,
    const float* __restrict__ wv, const float* __restrict__ fcw_f,
    unsigned short* __restrict__ Wc, unsigned short* __restrict__ fcw)
{
    int t = blockIdx.x * 256 + threadIdx.x;   // 65536 threads
    if (t < 16384)       Wc[t]           = f2h(wq[t]);
    else if (t < 32768)  Wc[t]           = f2h(wk[t - 16384]);
    else if (t < 49152)  Wc[t]           = f2h(wv[t - 32768]);
    else                 fcw[t - 49152]  = f2h(fcw_f[t - 49152]);
}

// ---------------- K1: QKV projection ----------------
// x:(b,128,L) fp32.  Out: Qp,Kp:(bh, l, 64) f16 token-major (Q scaled by log2e/8),
// Vp:(b, c, L) f16 d-major.
__global__ __launch_bounds__(256) void qkv_kernel(
    const float* __restrict__ x, const unsigned short* __restrict__ Wc,
    const float* __restrict__ bq, const float* __restrict__ bk, const float* __restrict__ bv,
    unsigned short* __restrict__ Qp, unsigned short* __restrict__ Kp, unsigned short* __restrict__ Vp)
{
    int blk = blockIdx.x;
    int b = blk >> 6;
    int l0 = (blk & 63) * 64;
    int tid = threadIdx.x;
    int wave = tid >> 6, lane = tid & 63;
    int c = lane & 15, qd = lane >> 4;

    __shared__ __align__(16) unsigned short Xs[64 * 128]; // [l][i], 16B chunk ci stored at ci^(l&15)

    #pragma unroll
    for (int it = 0; it < 8; ++it) {
        int i  = (tid >> 4) + 16 * it;
        int l4 = (tid & 15) * 4;
        const float4 v = *(const float4*)&x[(b * 128 + i) * L_SZ + l0 + l4];
        float vv[4] = {v.x, v.y, v.z, v.w};
        int ci = i >> 3;
        #pragma unroll
        for (int u = 0; u < 4; ++u) {
            int l = l4 + u;
            Xs[l * 128 + ((ci ^ (l & 15)) * 8) + (i & 7)] = f2h(vv[u]);
        }
    }
    __syncthreads();

    f16x8 afrag[4];
    #pragma unroll
    for (int kc = 0; kc < 4; ++kc) {
        int l = wave * 16 + c;
        int ci = kc * 4 + qd;
        afrag[kc] = *(const f16x8*)&Xs[l * 128 + ((ci ^ (l & 15)) * 8)];
    }

    f32x4 acc[24];
    #pragma unroll
    for (int nt = 0; nt < 24; ++nt) acc[nt] = (f32x4){0.f, 0.f, 0.f, 0.f};

    #pragma unroll
    for (int kc = 0; kc < 4; ++kc) {
        #pragma unroll
        for (int nt = 0; nt < 24; ++nt) {
            int o = nt * 16 + c;  // 0..383 row of Wc
            f16x8 bfrag = *(const f16x8*)&Wc[o * 128 + kc * 32 + qd * 8];
            acc[nt] = __builtin_amdgcn_mfma_f32_16x16x32_f16(afrag[kc], bfrag, acc[nt], 0, 0, 0);
        }
    }

    const float s_q = 0.18033688011f;  // log2(e)/8
    #pragma unroll
    for (int nt = 0; nt < 24; ++nt) {
        int p = nt >> 3;
        int o = (nt & 7) * 16 + c;     // 0..127
        int h = o >> 6, d = o & 63;
        #pragma unroll
        for (int r = 0; r < 4; ++r) {
            int l = l0 + wave * 16 + qd * 4 + r;
            float val = acc[nt][r];
            if (p == 0) {
                val = (val + bq[o]) * s_q;
                Qp[((b * 2 + h) * L_SZ + l) * 64 + d] = f2h(val);
            } else if (p == 1) {
                val += bk[o];
                Kp[((b * 2 + h) * L_SZ + l) * 64 + d] = f2h(val);
            } else {
                val += bv[o];
                Vp[(size_t)(b * 128 + o) * L_SZ + l] = f2h(val);
            }
        }
    }
}

// ---------------- K2: flash attention (transposed, 32x32 MFMA, kv-split 4) --
// Grid 1024 = sp(4) x bh(8) x ltile(32).  4 waves x 32 q-rows (BM=128, BN=64).
// Partials: Opart[sp][bh][d][l] f32 (unnormalized O^T), Mpart/Lpart[sp][bh][l].
__global__ __launch_bounds__(256, 4) void attn_kernel(
    const unsigned short* __restrict__ Qp, const unsigned short* __restrict__ Kp,
    const unsigned short* __restrict__ Vp,
    float* __restrict__ Opart, float* __restrict__ Mpart, float* __restrict__ Lpart)
{
    int blk = blockIdx.x;
    int lt = blk & 31;
    int bh = (blk >> 5) & 7;
    int sp = blk >> 8;
    int l0 = lt * 128;
    int tid = threadIdx.x;
    int wave = tid >> 6, lane = tid & 63;
    int ln = lane & 31, hi = lane >> 5;
    int b = bh >> 1, h = bh & 1;

    __shared__ __align__(16) unsigned short Ks[64 * 64];     // [m][d], chunk^(m&7)
    __shared__ __align__(16) unsigned short Vs[64 * 64];     // [d][m], chunk^(d&7)
    __shared__ __align__(16) unsigned short Ps[4 * 32 * 64]; // per-wave [l][m], chunk^(l&7)

    const unsigned short* Qb = Qp + (size_t)bh * L_SZ * 64;
    const unsigned short* Kb = Kp + (size_t)bh * L_SZ * 64;
    const unsigned short* Vb = Vp + ((size_t)b * 128 + h * 64) * L_SZ;

    int lq = l0 + wave * 32 + ln;
    f16x8 qf[4];   // B-operand: n = q-row (lane&31), k = d
    #pragma unroll
    for (int kc = 0; kc < 4; ++kc)
        qf[kc] = *(const f16x8*)&Qb[(size_t)lq * 64 + kc * 16 + hi * 8];

    float m_st = -1e30f, l_st = 0.f;
    f32x16 acc0 = {}, acc1 = {};   // O^T: rows d (0..31 / 32..63), col l=ln

    unsigned short* Pw = Ps + wave * 2048;
    int mglob = sp * 1024;

    for (int it = 0; it < 16; ++it) {
        int m0 = mglob + it * 64;
        uint4 kreg[2], vreg[2];
        #pragma unroll
        for (int j = 0; j < 2; ++j) {
            int u = tid + j * 256;
            int row = u >> 3, ci = u & 7;
            kreg[j] = *(const uint4*)&Kb[(size_t)(m0 + row) * 64 + ci * 8];
            vreg[j] = *(const uint4*)&Vb[(size_t)row * L_SZ + m0 + ci * 8];
        }
        __syncthreads();   // prior iter's Ks/Vs reads complete
        #pragma unroll
        for (int j = 0; j < 2; ++j) {
            int u = tid + j * 256;
            int row = u >> 3, ci = u & 7;
            *(uint4*)&Ks[row * 64 + ((ci ^ (row & 7)) * 8)] = kreg[j];
            *(uint4*)&Vs[row * 64 + ((ci ^ (row & 7)) * 8)] = vreg[j];
        }
        __syncthreads();

        // S^T[m][l] = K·Q^T : A = K rows m, B = Q rows l.  col(lane&31)=l.
        f32x16 s0 = {}, s1 = {};
        #pragma unroll
        for (int kc = 0; kc < 4; ++kc) {
            int cd = kc * 2 + hi;
            int r1 = 32 + ln;
            f16x8 k0 = *(const f16x8*)&Ks[ln * 64 + ((cd ^ (ln & 7)) * 8)];
            f16x8 k1 = *(const f16x8*)&Ks[r1 * 64 + ((cd ^ (r1 & 7)) * 8)];
            s0 = __builtin_amdgcn_mfma_f32_32x32x16_f16(k0, qf[kc], s0, 0, 0, 0);
            s1 = __builtin_amdgcn_mfma_f32_32x32x16_f16(k1, qf[kc], s1, 0, 0, 0);
        }

        // online softmax: all 32 in-lane scores belong to q-row l=ln
        float mx = s0[0];
        #pragma unroll
        for (int r = 1; r < 16; ++r) mx = fmaxf(mx, s0[r]);
        #pragma unroll
        for (int r = 0; r < 16; ++r) mx = fmaxf(mx, s1[r]);
        mx = fmaxf(mx, __shfl_xor(mx, 32));
        float mnew = fmaxf(m_st, mx);
        float alpha = exp2f(m_st - mnew);
        m_st = mnew;
        float rsum = 0.f;
        #pragma unroll
        for (int r = 0; r < 16; ++r) { float p = exp2f(s0[r] - mnew); s0[r] = p; rsum += p; }
        #pragma unroll
        for (int r = 0; r < 16; ++r) { float p = exp2f(s1[r] - mnew); s1[r] = p; rsum += p; }
        rsum += __shfl_xor(rsum, 32);
        l_st = l_st * alpha + rsum;
        #pragma unroll
        for (int r = 0; r < 16; ++r) { acc0[r] *= alpha; acc1[r] *= alpha; }

        // P -> LDS (C-layout rows m are 4-consecutive per reg group -> b64)
        #pragma unroll
        for (int g = 0; g < 4; ++g) {
            uint2 w0;
            w0.x = pk2(s0[g * 4 + 0], s0[g * 4 + 1]);
            w0.y = pk2(s0[g * 4 + 2], s0[g * 4 + 3]);
            *(uint2*)&Pw[ln * 64 + ((g ^ (ln & 7)) * 8) + hi * 4] = w0;
            uint2 w1;
            w1.x = pk2(s1[g * 4 + 0], s1[g * 4 + 1]);
            w1.y = pk2(s1[g * 4 + 2], s1[g * 4 + 3]);
            *(uint2*)&Pw[ln * 64 + (((4 + g) ^ (ln & 7)) * 8) + hi * 4] = w1;
        }
        // per-wave LDS: compiler lgkmcnt orders write->read, no barrier

        // O^T += V·P^T : A = V rows d, B = P rows l
        #pragma unroll
        for (int kc = 0; kc < 4; ++kc) {
            int cd = kc * 2 + hi;
            int r1 = 32 + ln;
            f16x8 pf = *(const f16x8*)&Pw[ln * 64 + ((cd ^ (ln & 7)) * 8)];
            f16x8 v0 = *(const f16x8*)&Vs[ln * 64 + ((cd ^ (ln & 7)) * 8)];
            f16x8 v1 = *(const f16x8*)&Vs[r1 * 64 + ((cd ^ (r1 & 7)) * 8)];
            acc0 = __builtin_amdgcn_mfma_f32_32x32x16_f16(v0, pf, acc0, 0, 0, 0);
            acc1 = __builtin_amdgcn_mfma_f32_32x32x16_f16(v1, pf, acc1, 0, 0, 0);
        }
    }

    // epilogue: raw partials
    float* Ow = Opart + (size_t)(sp * 8 + bh) * 64 * 4096;
    #pragma unroll
    for (int r = 0; r < 16; ++r) {
        int d0 = (r & 3) + 8 * (r >> 2) + 4 * hi;
        Ow[(size_t)d0 * 4096 + lq] = acc0[r];
        Ow[(size_t)(32 + d0) * 4096 + lq] = acc1[r];
    }
    if (hi == 0) {
        Mpart[(sp * 8 + bh) * 4096 + lq] = m_st;
        Lpart[(sp * 8 + bh) * 4096 + lq] = l_st;
    }
}

// ---------------- K2b: combine kv-split partials -> Ob f16 [bh*64+d][l] ----
__global__ __launch_bounds__(256) void combine_kernel(
    const float* __restrict__ Op, const float* __restrict__ Mp,
    const float* __restrict__ Lp, unsigned short* __restrict__ Ob)
{
    int t = blockIdx.x * 256 + threadIdx.x;   // 524288 threads, 4 elems each
    int e0 = t * 4;                            // flat (bh*64+d)*4096 + l
    int l = e0 & 4095;
    int bh = e0 >> 18;
    int mbase = bh * 4096 + l;

    float4 M[4], Lv[4];
    #pragma unroll
    for (int s = 0; s < 4; ++s) {
        M[s]  = *(const float4*)&Mp[s * 32768 + mbase];
        Lv[s] = *(const float4*)&Lp[s * 32768 + mbase];
    }
    float mx[4];
    #pragma unroll
    for (int u = 0; u < 4; ++u) {
        float m0 = ((const float*)&M[0])[u];
        #pragma unroll
        for (int s = 1; s < 4; ++s) m0 = fmaxf(m0, ((const float*)&M[s])[u]);
        mx[u] = m0;
    }
    float acc[4] = {0.f, 0.f, 0.f, 0.f}, lt[4] = {0.f, 0.f, 0.f, 0.f};
    #pragma unroll
    for (int s = 0; s < 4; ++s) {
        float4 o = *(const float4*)&Op[(size_t)s * 2097152 + e0];
        const float* ov = (const float*)&o;
        #pragma unroll
        for (int u = 0; u < 4; ++u) {
            float a = exp2f(((const float*)&M[s])[u] - mx[u]);
            acc[u] += a * ov[u];
            lt[u]  += a * ((const float*)&Lv[s])[u];
        }
    }
    unsigned int p0 = pk2(acc[0] / lt[0], acc[1] / lt[1]);
    unsigned int p1 = pk2(acc[2] / lt[2], acc[3] / lt[3]);
    *(uint2*)&Ob[e0] = make_uint2(p0, p1);
}

// ---------------- K3: fc (over last dim) + BN + PReLU ----------------
__global__ __launch_bounds__(256) void fc_kernel(
    const unsigned short* __restrict__ Ob, const unsigned short* __restrict__ fcw,
    const float* __restrict__ fc_b, const float* __restrict__ bn_g,
    const float* __restrict__ bn_b, const float* __restrict__ bn_m,
    const float* __restrict__ bn_v, const float* __restrict__ prelu_a,
    float* __restrict__ out)
{
    int tid = threadIdx.x;
    int wave = tid >> 6, lane = tid & 63;
    int c = lane & 15, qd = lane >> 4;
    int r0 = blockIdx.x * 64 + wave * 16;

    f16x8 af[4];
    #pragma unroll
    for (int kc = 0; kc < 4; ++kc)
        af[kc] = *(const f16x8*)&Ob[(size_t)(r0 + c) * 128 + kc * 32 + qd * 8];

    f32x4 acc[8];
    #pragma unroll
    for (int nt = 0; nt < 8; ++nt) acc[nt] = (f32x4){0.f, 0.f, 0.f, 0.f};

    #pragma unroll
    for (int kc = 0; kc < 4; ++kc) {
        #pragma unroll
        for (int nt = 0; nt < 8; ++nt) {
            f16x8 bf = *(const f16x8*)&fcw[(nt * 16 + c) * 128 + kc * 32 + qd * 8];
            acc[nt] = __builtin_amdgcn_mfma_f32_16x16x32_f16(af[kc], bf, acc[nt], 0, 0, 0);
        }
    }

    float pa = prelu_a[0];
    #pragma unroll
    for (int r = 0; r < 4; ++r) {
        int row = r0 + qd * 4 + r;
        int ch = (row >> 5) & 127;
        float g  = bn_g[ch] * rsqrtf(bn_v[ch] + 1e-5f);
        float mn = bn_m[ch], bt = bn_b[ch];
        #pragma unroll
        for (int nt = 0; nt < 8; ++nt) {
            int o = nt * 16 + c;
            float y = (acc[nt][r] + fc_b[o] - mn) * g + bt;
            y = y > 0.f ? y : pa * y;
            out[(size_t)row * 128 + o] = y;
        }
    }
}

extern "C" void kernel_launch(void* const* d_in, const int* in_sizes, int n_in,
                              void* d_out, int out_size, void* d_ws, size_t ws_size,
                              hipStream_t stream) {
    const float* x     = (const float*)d_in[0];
    const float* wq    = (const float*)d_in[1];
    const float* bq    = (const float*)d_in[2];
    const float* wk    = (const float*)d_in[3];
    const float* bk    = (const float*)d_in[4];
    const float* wv    = (const float*)d_in[5];
    const float* bv    = (const float*)d_in[6];
    const float* fcw_f = (const float*)d_in[7];
    const float* fcb   = (const float*)d_in[8];
    const float* bn_g  = (const float*)d_in[9];
    const float* bn_b  = (const float*)d_in[10];
    const float* bn_m  = (const float*)d_in[11];
    const float* bn_v  = (const float*)d_in[12];
    const float* pa    = (const float*)d_in[13];
    float* out = (float*)d_out;

    unsigned short* Wc  = (unsigned short*)d_ws;   // 384*128
    unsigned short* fcw = Wc + 384 * 128;          // 128*128
    unsigned short* Qp  = fcw + 128 * 128;
    unsigned short* Kp  = Qp + 8 * L_SZ * 64;
    unsigned short* Vp  = Kp + 8 * L_SZ * 64;
    unsigned short* Obf = Vp + 8 * L_SZ * 64;
    float* Opart = (float*)(Obf + 8 * L_SZ * 64);  // 4*8*64*4096 f32
    float* Mpart = Opart + 4 * 8 * 64 * L_SZ;      // 4*8*4096
    float* Lpart = Mpart + 4 * 8 * L_SZ;

    hipLaunchKernelGGL(cvt_kernel,     dim3(256),  dim3(256), 0, stream, wq, wk, wv, fcw_f, Wc, fcw);
    hipLaunchKernelGGL(qkv_kernel,     dim3(256),  dim3(256), 0, stream, x, Wc, bq, bk, bv, Qp, Kp, Vp);
    hipLaunchKernelGGL(attn_kernel,    dim3(1024), dim3(256), 0, stream, Qp, Kp, Vp, Opart, Mpart, Lpart);
    hipLaunchKernelGGL(combine_kernel, dim3(2048), dim3(256), 0, stream, Opart, Mpart, Lpart, Obf);
    hipLaunchKernelGGL(fc_kernel,      dim3(256),  dim3(256), 0, stream, Obf, fcw, fcb, bn_g, bn_b, bn_m, bn_v, pa, out);
}

// Round 4
// 170.051 us; speedup vs baseline: 1.6983x; 1.2595x over previous
//
#include <hip/hip_runtime.h>

typedef _Float16 f16x8 __attribute__((ext_vector_type(8)));
typedef _Float16 f16x4t __attribute__((ext_vector_type(4)));
typedef __fp16 h16x2 __attribute__((ext_vector_type(2)));
typedef float f32x4 __attribute__((ext_vector_type(4)));
typedef float f32x16 __attribute__((ext_vector_type(16)));

#define L_SZ 4096

__device__ __forceinline__ unsigned short f2h(float f) {
    _Float16 h = (_Float16)f;
    return __builtin_bit_cast(unsigned short, h);
}
__device__ __forceinline__ unsigned int pk2(float a, float b) {
    h16x2 p = __builtin_amdgcn_cvt_pkrtz(a, b);
    return __builtin_bit_cast(unsigned int, p);
}

// LDS slot for 64-row x 8-chunk (16B) K/V tiles: chunk-major, 3-bit row^chunk xor.
// Reads per (chunk,half) are contiguous 512B (conflict-free); writes ~2-way.
#define SLOT(row, ci) ((((ci) * 64) + ((row) & 32) + (((row) & 31) ^ (ci))) * 8)

// ---------------- K1: QKV projection (weights converted in-block) ----------
// x:(b,128,L) fp32. Out: Qp,Kp:(bh,l,64) f16 (Q scaled log2e/8), Vp:(b,c,L) f16.
__global__ __launch_bounds__(256, 1) void qkv_kernel(
    const float* __restrict__ x,
    const float* __restrict__ wq, const float* __restrict__ bq,
    const float* __restrict__ wk, const float* __restrict__ bk,
    const float* __restrict__ wv, const float* __restrict__ bv,
    unsigned short* __restrict__ Qp, unsigned short* __restrict__ Kp,
    unsigned short* __restrict__ Vp)
{
    int blk = blockIdx.x;
    int bidx = blk >> 6;
    int l0 = (blk & 63) * 64;
    int tid = threadIdx.x;
    int wave = tid >> 6, lane = tid & 63;
    int c = lane & 15, qd = lane >> 4;

    __shared__ __align__(16) unsigned short Ws[384 * 128]; // 96KB; chunk pos = ci^(o&15)
    __shared__ __align__(16) unsigned short Sc[9216];      // union: Xs(8192) / Vt(128x72)

    // ---- weights fp32 -> f16 LDS (49152 elems, float2 per lane, coalesced)
    #pragma unroll
    for (int t = 0; t < 96; ++t) {
        int e2 = tid + t * 256;          // float2 index
        const float* src = (e2 < 8192) ? wq : (e2 < 16384 ? wk : wv);
        int eo = (e2 * 2) & 16383;
        float2 v = *(const float2*)&src[eo];
        int e = e2 * 2;
        int o = e >> 7, ci = (e & 127) >> 3, j = e & 7;
        *(unsigned int*)&Ws[o * 128 + ((ci ^ (o & 15)) * 8) + j] = pk2(v.x, v.y);
    }

    // ---- stage x tile into Xs
    unsigned short* Xs = Sc;
    #pragma unroll
    for (int it = 0; it < 8; ++it) {
        int i  = (tid >> 4) + 16 * it;
        int l4 = (tid & 15) * 4;
        const float4 v = *(const float4*)&x[(bidx * 128 + i) * L_SZ + l0 + l4];
        float vv[4] = {v.x, v.y, v.z, v.w};
        int ci = i >> 3;
        #pragma unroll
        for (int u = 0; u < 4; ++u) {
            int l = l4 + u;
            Xs[l * 128 + ((ci ^ (l & 15)) * 8) + (i & 7)] = f2h(vv[u]);
        }
    }
    __syncthreads();

    f16x8 afrag[4];
    #pragma unroll
    for (int kc = 0; kc < 4; ++kc) {
        int l = wave * 16 + c;
        int ci = kc * 4 + qd;
        afrag[kc] = *(const f16x8*)&Xs[l * 128 + ((ci ^ (l & 15)) * 8)];
    }
    __syncthreads();   // all Xs reads done before Vt overwrites Sc

    f32x4 acc[24];
    #pragma unroll
    for (int nt = 0; nt < 24; ++nt) acc[nt] = (f32x4){0.f, 0.f, 0.f, 0.f};

    #pragma unroll
    for (int kc = 0; kc < 4; ++kc) {
        #pragma unroll
        for (int nt = 0; nt < 24; ++nt) {
            int o = nt * 16 + c;   // 0..383, o&15 == c
            f16x8 bfrag = *(const f16x8*)&Ws[o * 128 + (((kc * 4 + qd) ^ c) * 8)];
            acc[nt] = __builtin_amdgcn_mfma_f32_16x16x32_f16(afrag[kc], bfrag, acc[nt], 0, 0, 0);
        }
    }

    unsigned short* Vt = Sc;   // [o][72] pad to break banks
    const float s_q = 0.18033688011f;  // log2(e)/8
    #pragma unroll
    for (int nt = 0; nt < 24; ++nt) {
        int p = nt >> 3;
        int o = (nt & 7) * 16 + c;     // 0..127
        int h = o >> 6, d = o & 63;
        #pragma unroll
        for (int r = 0; r < 4; ++r) {
            int ll = wave * 16 + qd * 4 + r;
            int l = l0 + ll;
            float val = acc[nt][r];
            if (p == 0) {
                val = (val + bq[o]) * s_q;
                Qp[((bidx * 2 + h) * L_SZ + l) * 64 + d] = f2h(val);
            } else if (p == 1) {
                val += bk[o];
                Kp[((bidx * 2 + h) * L_SZ + l) * 64 + d] = f2h(val);
            } else {
                val += bv[o];
                Vt[o * 72 + ll] = f2h(val);
            }
        }
    }
    __syncthreads();
    // cooperative coalesced V store: 128 rows x 64 l
    #pragma unroll
    for (int t = 0; t < 2; ++t) {
        int u = tid + t * 256;          // 0..511
        int row = u >> 2;               // 0..127
        int lc = (u & 3) * 16;          // 16 l (32B) per thread
        uint4 a0 = *(const uint4*)&Vt[row * 72 + lc];
        uint4 a1 = *(const uint4*)&Vt[row * 72 + lc + 8];
        *(uint4*)&Vp[(size_t)(bidx * 128 + row) * L_SZ + l0 + lc] = a0;
        *(uint4*)&Vp[(size_t)(bidx * 128 + row) * L_SZ + l0 + lc + 8] = a1;
    }
}

// ---------------- K2: flash attention (dbuf pipeline, conflict-free LDS) ---
// Grid 1024 = sp(4) x bh(8) x ltile(32). 4 waves x 32 q-rows.
// Opart f16 [sp][bh][d][l] unnormalized; Mpart/Lpart f32 [sp][bh][l].
__global__ __launch_bounds__(256, 3) void attn_kernel(
    const unsigned short* __restrict__ Qp, const unsigned short* __restrict__ Kp,
    const unsigned short* __restrict__ Vp,
    unsigned short* __restrict__ Opart, float* __restrict__ Mpart, float* __restrict__ Lpart)
{
    int blk = blockIdx.x;
    int lt = blk & 31;
    int bh = (blk >> 5) & 7;
    int sp = blk >> 8;
    int l0 = lt * 128;
    int tid = threadIdx.x;
    int wave = tid >> 6, lane = tid & 63;
    int ln = lane & 31, hi = lane >> 5;
    int b = bh >> 1, h = bh & 1;

    __shared__ __align__(16) unsigned short Ks[2][4096];
    __shared__ __align__(16) unsigned short Vs[2][4096];
    __shared__ __align__(16) unsigned short Ps[4][2048];

    const unsigned short* Qb = Qp + (size_t)bh * L_SZ * 64;
    const unsigned short* Kb = Kp + (size_t)bh * L_SZ * 64;
    const unsigned short* Vb = Vp + ((size_t)b * 128 + h * 64) * L_SZ;

    int lq = l0 + wave * 32 + ln;
    f16x8 qf[4];   // B-operand: n = q-row ln, k chunks
    #pragma unroll
    for (int kc = 0; kc < 4; ++kc)
        qf[kc] = *(const f16x8*)&Qb[(size_t)lq * 64 + kc * 16 + hi * 8];

    float m_st = -1e30f, lsum = 0.f;
    f32x16 acc0 = {}, acc1 = {};

    int urow = tid >> 3, uci = tid & 7;   // staging assignment (rows 0..31 / +32)
    int mglob = sp * 1024;

    uint4 kreg[2], vreg[2];
    // prologue: tile 0
    #pragma unroll
    for (int j = 0; j < 2; ++j) {
        int row = urow + j * 32;
        kreg[j] = *(const uint4*)&Kb[(size_t)(mglob + row) * 64 + uci * 8];
        vreg[j] = *(const uint4*)&Vb[(size_t)row * L_SZ + mglob + uci * 8];
    }
    #pragma unroll
    for (int j = 0; j < 2; ++j) {
        int row = urow + j * 32;
        *(uint4*)&Ks[0][SLOT(row, uci)] = kreg[j];
        *(uint4*)&Vs[0][SLOT(row, uci)] = vreg[j];
    }

    for (int it = 0; it < 16; ++it) {
        int cur = it & 1;
        __syncthreads();                       // buf[cur] ready for everyone
        if (it < 15) {                         // prefetch next tile to regs
            int m0 = mglob + (it + 1) * 64;
            #pragma unroll
            for (int j = 0; j < 2; ++j) {
                int row = urow + j * 32;
                kreg[j] = *(const uint4*)&Kb[(size_t)(m0 + row) * 64 + uci * 8];
                vreg[j] = *(const uint4*)&Vb[(size_t)row * L_SZ + m0 + uci * 8];
            }
        }

        // S^T = K . Q^T
        f32x16 s0 = {}, s1 = {};
        #pragma unroll
        for (int kc = 0; kc < 4; ++kc) {
            int cd = kc * 2 + hi;
            f16x8 k0 = *(const f16x8*)&Ks[cur][SLOT(ln, cd)];
            f16x8 k1 = *(const f16x8*)&Ks[cur][SLOT(32 + ln, cd)];
            s0 = __builtin_amdgcn_mfma_f32_32x32x16_f16(k0, qf[kc], s0, 0, 0, 0);
            s1 = __builtin_amdgcn_mfma_f32_32x32x16_f16(k1, qf[kc], s1, 0, 0, 0);
        }

        // online softmax (base-2); lsum kept per half-lane, merged at end
        float mx = s0[0];
        #pragma unroll
        for (int r = 1; r < 16; ++r) mx = fmaxf(mx, s0[r]);
        #pragma unroll
        for (int r = 0; r < 16; ++r) mx = fmaxf(mx, s1[r]);
        mx = fmaxf(mx, __shfl_xor(mx, 32));
        float mnew = fmaxf(m_st, mx);
        float alpha = exp2f(m_st - mnew);
        m_st = mnew;
        float rsum = 0.f;
        #pragma unroll
        for (int r = 0; r < 16; ++r) { float p = exp2f(s0[r] - mnew); s0[r] = p; rsum += p; }
        #pragma unroll
        for (int r = 0; r < 16; ++r) { float p = exp2f(s1[r] - mnew); s1[r] = p; rsum += p; }
        lsum = lsum * alpha + rsum;
        #pragma unroll
        for (int r = 0; r < 16; ++r) { acc0[r] *= alpha; acc1[r] *= alpha; }

        // P -> per-wave LDS (chunk-major slots, halves interleave banks)
        #pragma unroll
        for (int g = 0; g < 4; ++g) {
            uint2 w0;
            w0.x = pk2(s0[g * 4 + 0], s0[g * 4 + 1]);
            w0.y = pk2(s0[g * 4 + 2], s0[g * 4 + 3]);
            *(uint2*)&Ps[wave][(g * 32 + (ln ^ g)) * 8 + hi * 4] = w0;
            int g2 = 4 + g;
            uint2 w1;
            w1.x = pk2(s1[g * 4 + 0], s1[g * 4 + 1]);
            w1.y = pk2(s1[g * 4 + 2], s1[g * 4 + 3]);
            *(uint2*)&Ps[wave][(g2 * 32 + (ln ^ g2)) * 8 + hi * 4] = w1;
        }

        // O^T += V . P^T
        #pragma unroll
        for (int kc = 0; kc < 4; ++kc) {
            int cd = kc * 2 + hi;
            f16x8 pf = *(const f16x8*)&Ps[wave][(cd * 32 + (ln ^ cd)) * 8];
            f16x8 v0 = *(const f16x8*)&Vs[cur][SLOT(ln, cd)];
            f16x8 v1 = *(const f16x8*)&Vs[cur][SLOT(32 + ln, cd)];
            acc0 = __builtin_amdgcn_mfma_f32_32x32x16_f16(v0, pf, acc0, 0, 0, 0);
            acc1 = __builtin_amdgcn_mfma_f32_32x32x16_f16(v1, pf, acc1, 0, 0, 0);
        }

        if (it < 15) {                         // stage next tile (buf free: all waves past barrier)
            #pragma unroll
            for (int j = 0; j < 2; ++j) {
                int row = urow + j * 32;
                *(uint4*)&Ks[cur ^ 1][SLOT(row, uci)] = kreg[j];
                *(uint4*)&Vs[cur ^ 1][SLOT(row, uci)] = vreg[j];
            }
        }
    }

    float l_tot = lsum + __shfl_xor(lsum, 32);
    unsigned short* Ow = Opart + (size_t)(sp * 8 + bh) * 64 * 4096;
    #pragma unroll
    for (int r = 0; r < 16; ++r) {
        int d0 = (r & 3) + 8 * (r >> 2) + 4 * hi;
        Ow[(size_t)d0 * 4096 + lq] = f2h(acc0[r]);
        Ow[(size_t)(32 + d0) * 4096 + lq] = f2h(acc1[r]);
    }
    if (hi == 0) {
        Mpart[(sp * 8 + bh) * 4096 + lq] = m_st;
        Lpart[(sp * 8 + bh) * 4096 + lq] = l_tot;
    }
}

// ---------------- K3: combine + fc + BN + PReLU ----------------
// Rows r=(b*128+c)*32+h; block = 64 rows (single bh per block). out fp32.
__global__ __launch_bounds__(256, 1) void fc_kernel(
    const unsigned short* __restrict__ Opart, const float* __restrict__ Mp,
    const float* __restrict__ Lp, const float* __restrict__ fcw_f,
    const float* __restrict__ fc_b, const float* __restrict__ bn_g,
    const float* __restrict__ bn_b, const float* __restrict__ bn_m,
    const float* __restrict__ bn_v, const float* __restrict__ prelu_a,
    float* __restrict__ out)
{
    int blk = blockIdx.x;
    int r0 = blk * 64;
    int tid = threadIdx.x;
    int c0 = (r0 >> 5) & 127;              // even -> block never straddles heads
    int bh = (r0 >> 12) * 2 + (c0 >> 6);

    __shared__ __align__(16) unsigned short Fw[128 * 128];   // 32KB
    __shared__ __align__(16) unsigned short SclU[4096 * 4];  // 32KB: f16x4 scales per l-slot

    // scales: slot(l) = h*128 + ((w + h)&127)
    #pragma unroll
    for (int t = 0; t < 16; ++t) {
        int l = tid + t * 256;
        float m0 = Mp[(0 * 8 + bh) * 4096 + l], m1 = Mp[(1 * 8 + bh) * 4096 + l];
        float m2 = Mp[(2 * 8 + bh) * 4096 + l], m3 = Mp[(3 * 8 + bh) * 4096 + l];
        float mx = fmaxf(fmaxf(m0, m1), fmaxf(m2, m3));
        float a0 = exp2f(m0 - mx), a1 = exp2f(m1 - mx);
        float a2 = exp2f(m2 - mx), a3 = exp2f(m3 - mx);
        float den = a0 * Lp[(0 * 8 + bh) * 4096 + l] + a1 * Lp[(1 * 8 + bh) * 4096 + l]
                  + a2 * Lp[(2 * 8 + bh) * 4096 + l] + a3 * Lp[(3 * 8 + bh) * 4096 + l];
        float inv = 1.0f / den;
        int hh = l >> 7, ww = l & 127;
        int slot = hh * 128 + ((ww + hh) & 127);
        uint2 sc;
        sc.x = pk2(a0 * inv, a1 * inv);
        sc.y = pk2(a2 * inv, a3 * inv);
        *(uint2*)&SclU[slot * 4] = sc;
    }
    // fcw fp32 -> f16 LDS, chunk pos ci^(o&15)
    #pragma unroll
    for (int t = 0; t < 32; ++t) {
        int e2 = tid + t * 256;
        float2 v = *(const float2*)&fcw_f[e2 * 2];
        int e = e2 * 2;
        int o = e >> 7, ci = (e & 127) >> 3, j = e & 7;
        *(unsigned int*)&Fw[o * 128 + ((ci ^ (o & 15)) * 8) + j] = pk2(v.x, v.y);
    }
    __syncthreads();

    int wave = tid >> 6, lane = tid & 63;
    int c = lane & 15, qd = lane >> 4;
    int rw = r0 + wave * 16;
    int row = rw + c;
    int ch = (row >> 5) & 127, hh = row & 31, d = ch & 63;

    // A-frags: combine 4 splits with scales
    f16x8 af[4];
    #pragma unroll
    for (int kc = 0; kc < 4; ++kc) {
        int w0 = kc * 32 + qd * 8;
        f16x8 ov[4];
        #pragma unroll
        for (int s = 0; s < 4; ++s)
            ov[s] = *(const f16x8*)&Opart[(size_t)(s * 8 + bh) * 262144 + (size_t)d * 4096 + hh * 128 + w0];
        #pragma unroll
        for (int j = 0; j < 8; ++j) {
            int slot = hh * 128 + ((w0 + j + hh) & 127);
            f16x4t sc = *(const f16x4t*)&SclU[slot * 4];
            float v = (float)ov[0][j] * (float)sc[0] + (float)ov[1][j] * (float)sc[1]
                    + (float)ov[2][j] * (float)sc[2] + (float)ov[3][j] * (float)sc[3];
            af[kc][j] = (_Float16)v;
        }
    }

    f32x4 acc[8];
    #pragma unroll
    for (int nt = 0; nt < 8; ++nt) acc[nt] = (f32x4){0.f, 0.f, 0.f, 0.f};
    #pragma unroll
    for (int kc = 0; kc < 4; ++kc) {
        #pragma unroll
        for (int nt = 0; nt < 8; ++nt) {
            int o = nt * 16 + c;
            f16x8 bf = *(const f16x8*)&Fw[o * 128 + (((kc * 4 + qd) ^ c) * 8)];
            acc[nt] = __builtin_amdgcn_mfma_f32_16x16x32_f16(af[kc], bf, acc[nt], 0, 0, 0);
        }
    }

    float pa = prelu_a[0];
    #pragma unroll
    for (int r = 0; r < 4; ++r) {
        int orow = rw + qd * 4 + r;
        int chn = (orow >> 5) & 127;
        float g  = bn_g[chn] * rsqrtf(bn_v[chn] + 1e-5f);
        float mn = bn_m[chn], bt = bn_b[chn];
        #pragma unroll
        for (int nt = 0; nt < 8; ++nt) {
            int o = nt * 16 + c;
            float y = (acc[nt][r] + fc_b[o] - mn) * g + bt;
            y = y > 0.f ? y : pa * y;
            out[(size_t)orow * 128 + o] = y;
        }
    }
}

extern "C" void kernel_launch(void* const* d_in, const int* in_sizes, int n_in,
                              void* d_out, int out_size, void* d_ws, size_t ws_size,
                              hipStream_t stream) {
    const float* x     = (const float*)d_in[0];
    const float* wq    = (const float*)d_in[1];
    const float* bq    = (const float*)d_in[2];
    const float* wk    = (const float*)d_in[3];
    const float* bk    = (const float*)d_in[4];
    const float* wv    = (const float*)d_in[5];
    const float* bv    = (const float*)d_in[6];
    const float* fcw_f = (const float*)d_in[7];
    const float* fcb   = (const float*)d_in[8];
    const float* bn_g  = (const float*)d_in[9];
    const float* bn_b  = (const float*)d_in[10];
    const float* bn_m  = (const float*)d_in[11];
    const float* bn_v  = (const float*)d_in[12];
    const float* pa    = (const float*)d_in[13];
    float* out = (float*)d_out;

    unsigned short* Qp  = (unsigned short*)d_ws;
    unsigned short* Kp  = Qp + 8 * L_SZ * 64;
    unsigned short* Vp  = Kp + 8 * L_SZ * 64;
    unsigned short* Opart = Vp + 8 * L_SZ * 64;   // f16, 4*8*64*4096
    float* Mpart = (float*)(Opart + 4 * 8 * 64 * L_SZ);
    float* Lpart = Mpart + 4 * 8 * L_SZ;

    hipLaunchKernelGGL(qkv_kernel,  dim3(256),  dim3(256), 0, stream,
                       x, wq, bq, wk, bk, wv, bv, Qp, Kp, Vp);
    hipLaunchKernelGGL(attn_kernel, dim3(1024), dim3(256), 0, stream,
                       Qp, Kp, Vp, Opart, Mpart, Lpart);
    hipLaunchKernelGGL(fc_kernel,   dim3(256),  dim3(256), 0, stream,
                       Opart, Mpart, Lpart, fcw_f, fcb, bn_g, bn_b, bn_m, bn_v, pa, out);
}